// Round 10
// baseline (150.561 us; speedup 1.0000x reference)
//
#include <hip/hip_runtime.h>
#include <hip/hip_bf16.h>

typedef unsigned short u16;
typedef __attribute__((ext_vector_type(8))) short short8;   // 8 bf16 = 4 VGPRs
typedef __attribute__((ext_vector_type(4))) float f32x4;

#define BATCH 64
#define SEQ   256
#define CDIM  384
#define NHEAD 6
#define DHEAD 64
#define NROW  16384   // BATCH*SEQ

constexpr float SCALE = 0.051031036307982884f;  // 384^-0.5

__device__ __forceinline__ f32x4 mfma16(short8 a, short8 b, f32x4 c) {
    return __builtin_amdgcn_mfma_f32_16x16x32_bf16(a, b, c, 0, 0, 0);
}

__device__ __forceinline__ u16 f2b(float f) {
    __hip_bfloat16 h = __float2bfloat16(f);
    return *reinterpret_cast<u16*>(&h);
}

__device__ __forceinline__ void gload_lds16(const u16* g, u16* l) {
    __builtin_amdgcn_global_load_lds(
        (const __attribute__((address_space(1))) void*)g,
        (__attribute__((address_space(3))) void*)l, 16, 0, 0);
}

// ---------------------------------------------------------------------------
// fp32 -> bf16 conversion for x AND the 4 weights, one launch.
// blocks [0,3072): x (6291456 elems); [3072,3360): weights, 72 blocks each.
// ---------------------------------------------------------------------------
__global__ __launch_bounds__(256) void cvt_all(
        const float* __restrict__ x,
        const float* __restrict__ Wk, const float* __restrict__ Wq,
        const float* __restrict__ Wv, const float* __restrict__ Wo,
        u16* __restrict__ xb,
        u16* __restrict__ wkb, u16* __restrict__ wqb,
        u16* __restrict__ wvb, u16* __restrict__ wob)
{
    int blk = blockIdx.x;
    const float* s;
    u16* d;
    if (blk < 3072) {
        s = x; d = xb;
    } else {
        const int w = blk - 3072;
        const int z = w / 72;           // 0..3
        blk = w - z * 72;
        s = (z == 0) ? Wk : (z == 1) ? Wq : (z == 2) ? Wv : Wo;
        d = (z == 0) ? wkb : (z == 1) ? wqb : (z == 2) ? wvb : wob;
    }
    const int i = (blk * 256 + (int)threadIdx.x) * 8;
    const float4 a = *(const float4*)(s + i);
    const float4 b = *(const float4*)(s + i + 4);
    short8 r;
    r[0] = (short)f2b(a.x); r[1] = (short)f2b(a.y);
    r[2] = (short)f2b(a.z); r[3] = (short)f2b(a.w);
    r[4] = (short)f2b(b.x); r[5] = (short)f2b(b.y);
    r[6] = (short)f2b(b.z); r[7] = (short)f2b(b.w);
    *(short8*)(d + i) = r;
}

// ---------------------------------------------------------------------------
// QKV projection (all-bf16): Y = X @ W^T. 128x128 tile, BK=64, 4 waves @
// 64x64. 2-phase pipeline: double-buffered LDS, raw s_barrier + counted
// vmcnt(8) (proven R9: keeps next tile's DMA in flight across the barrier).
// XCD-aware block swizzle: 1152 = 8 XCD x 16 panels x 9 sharers, bijective.
//   z=0: K -> ws  [B,H,T,D]    z=1: V -> d_out [B,H,D,T] (transposed)
//   z=2: Q -> ws  [B,H,T,D]
// ---------------------------------------------------------------------------
__global__ __launch_bounds__(256) void gemm_qkv(
        const u16* __restrict__ X, const u16* __restrict__ Wk,
        const u16* __restrict__ Wv, const u16* __restrict__ Wq,
        u16* __restrict__ Kd, u16* __restrict__ VTd, u16* __restrict__ Qd)
{
    __shared__ u16 SMEM[32768];   // 64 KB: buf b = [As 8192 | Bs 8192] at b*16384

    const int bid   = blockIdx.x;        // 0..1151
    const int xcd   = bid & 7;
    const int i     = bid >> 3;          // 0..143
    const int igrp  = i / 9;             // 0..15
    const int j     = i - igrp * 9;      // 0..8
    const int panel = xcd * 16 + igrp;   // 0..127
    const int m0    = panel * 128;
    const int n0    = (j % 3) * 128;
    const int z     = j / 3;
    const u16* W = (z == 0) ? Wk : (z == 1 ? Wv : Wq);

    const int tid  = threadIdx.x;
    const int lane = tid & 63;
    const int wv   = tid >> 6;
    const int l15  = lane & 15;
    const int q4   = lane >> 4;
    const int wm   = (wv >> 1) * 64;
    const int wn   = (wv & 1) * 64;

    f32x4 acc[4][4] = {};

    auto STAGE = [&](int kk, int buf) {
#pragma unroll
        for (int ch = 0; ch < 4; ++ch) {
            const int f  = (ch * 256 + tid) * 8;
            const int r  = f >> 6;
            const int cb = (f ^ ((r & 7) << 3)) & 63;   // inverse-swizzled col
            const int lb = buf * 16384 + (ch * 256 + wv * 64) * 8;
            gload_lds16(X + (size_t)(m0 + r) * CDIM + kk + cb, SMEM + lb);
            gload_lds16(W + (size_t)(n0 + r) * CDIM + kk + cb, SMEM + 8192 + lb);
        }
    };

    STAGE(0, 0);
#pragma unroll
    for (int t = 0; t < 6; ++t) {
        const int cur = t & 1;
        if (t < 5) {
            STAGE((t + 1) * 64, cur ^ 1);
            asm volatile("s_waitcnt vmcnt(8)" ::: "memory");  // tile t's 8 done
        } else {
            asm volatile("s_waitcnt vmcnt(0)" ::: "memory");
        }
        asm volatile("s_barrier" ::: "memory");   // tile t visible, prefetch live

        const u16* As = SMEM + cur * 16384;
        const u16* Bs = SMEM + cur * 16384 + 8192;
#pragma unroll
        for (int ks = 0; ks < 2; ++ks) {
            short8 af[4], bf[4];
#pragma unroll
            for (int tt = 0; tt < 4; ++tt) {
                const int ra = wm + tt * 16 + l15;
                const int rb = wn + tt * 16 + l15;
                af[tt] = *(const short8*)(As + ra * 64 +
                        ((ks * 32 + q4 * 8) ^ ((ra & 7) << 3)));
                bf[tt] = *(const short8*)(Bs + rb * 64 +
                        ((ks * 32 + q4 * 8) ^ ((rb & 7) << 3)));
            }
#pragma unroll
            for (int tm = 0; tm < 4; ++tm)
#pragma unroll
                for (int tn = 0; tn < 4; ++tn)
                    acc[tm][tn] = mfma16(af[tm], bf[tn], acc[tm][tn]);
        }
        asm volatile("s_barrier" ::: "memory");   // buf free for next overwrite
    }

    if (z != 1) {
        // ---- coalesced epilogue to [B,H,T,D] via LDS --------------------
        u16* D = (z == 0) ? Kd : Qd;
        u16* T = SMEM;                    // [128 t][128 col], XOR chunk-swz
#pragma unroll
        for (int tm = 0; tm < 4; ++tm)
#pragma unroll
            for (int tn = 0; tn < 4; ++tn) {
                const int cl = wn + tn * 16 + l15;
#pragma unroll
                for (int r = 0; r < 4; ++r) {
                    const int row = wm + tm * 16 + q4 * 4 + r;
                    T[row * 128 + (((cl >> 3) ^ (row & 7)) << 3) + (cl & 7)] =
                        f2b(acc[tm][tn][r]);
                }
            }
        __syncthreads();
        const int seg0 = tid >> 3;        // 0..31
        const int c    = tid & 7;         // 16B chunk within 64-d segment
#pragma unroll
        for (int it = 0; it < 8; ++it) {
            const int S   = it * 32 + seg0;   // 0..255: (row, head-half)
            const int row = S >> 1;
            const int hf  = S & 1;
            const int rowg = m0 + row;
            const int b  = rowg >> 8, tt = rowg & 255;
            const int h  = (n0 + hf * 64) >> 6;
            const int chunk = (hf * 8 + c) ^ (row & 7);
            *(uint4*)(D + (size_t)((b * NHEAD + h) * SEQ + tt) * DHEAD + c * 8) =
                *(const uint4*)(T + row * 128 + chunk * 8);
        }
    } else {
        // ---- transpose epilogue: V^T [B,H,D,T] --------------------------
        u16* T = SMEM;                    // [128 feat][136]
#pragma unroll
        for (int tm = 0; tm < 4; ++tm)
#pragma unroll
            for (int tn = 0; tn < 4; ++tn) {
                const int cl = wn + tn * 16 + l15;            // feature-local
#pragma unroll
                for (int r = 0; r < 4; ++r) {
                    const int rl = wm + tm * 16 + q4 * 4 + r; // t-local
                    T[cl * 136 + rl] = f2b(acc[tm][tn][r]);
                }
            }
        __syncthreads();
        const int b  = m0 >> 8;
        const int t0 = m0 & 255;
        const int fl = tid >> 1;          // feature-local 0..127
        const int hf = tid & 1;           // which 64-t half
        const int fg = n0 + fl;
        const int h  = fg >> 6, d = fg & 63;
        u16* dst = VTd + ((size_t)(b * NHEAD + h) * DHEAD + d) * SEQ + t0 + hf * 64;
        const u16* src = T + fl * 136 + hf * 64;
#pragma unroll
        for (int j2 = 0; j2 < 8; ++j2)
            *(uint4*)(dst + j2 * 8) = *(const uint4*)(src + j2 * 8);
    }
}

// ---------------------------------------------------------------------------
// Attention: 64 query rows per block, causal keys [0,64(CH+1)).
// T14 issue-early/write-late staging: ph1 K prefetched into regs during ph0
// QK^T; ph0 V loads issued before softmax (latency hides under it); ph1 V
// loads issued before PV-ph0 compute. LDS footprint unchanged (51 KB).
// XCD swizzle: all 4 chunk-blocks of one bh on ONE XCD (K/V L2-local).
// O written row-major [NROW][CDIM] bf16 (coalesced uint4 via LDS).
// ---------------------------------------------------------------------------
#define PLD 264   // P panel leading dim (u16): mult of 8 (16B align), 2-way banks

template <int CH>
__device__ __forceinline__ void attn_body(
        const u16* __restrict__ Qg, const u16* __restrict__ Kg,
        const u16* __restrict__ VTg, u16* __restrict__ Og, int bh,
        u16* SA, u16* Pbase)
{
    constexpr int NKEY = 64 * (CH + 1);
    constexpr int KT   = NKEY / 16;
    constexpr int NPH  = (NKEY + 127) / 128;
    constexpr int R0   = (NKEY < 128) ? NKEY : 128;   // keys in phase 0
    constexpr int R1   = NKEY - R0;                   // keys in phase 1

    const int tid  = threadIdx.x;
    const int wv   = tid >> 6;
    const int lane = tid & 63;
    const int l15  = lane & 15;
    const int q4   = lane >> 4;
    const int qrow0 = CH * 64 + wv * 16;
    const int qmax  = qrow0 + 15;
    u16* Pl = Pbase + wv * 16 * PLD;     // per-wave P panel [16 q][PLD]

    short8 aq[2];
#pragma unroll
    for (int ks = 0; ks < 2; ++ks)
        aq[ks] = *(const short8*)(Qg + (size_t)(bh * SEQ + qrow0 + l15) * DHEAD
                                     + ks * 32 + q4 * 8);

    // ---- S = Q K^T * scale, causal; ph1 K prefetched into regs ----------
    u16* Kbuf = SA;                      // [128][72]
    f32x4 s[KT];
    const int kr = tid >> 3;             // staging row group 0..31
    const int kd = (tid & 7) * 8;        // staging col chunk

    // ph0 K stage (nothing to hide under yet)
#pragma unroll
    for (int it = 0; it < R0 / 32; ++it) {
        const int r = it * 32 + kr;
        *(uint4*)(Kbuf + r * 72 + kd) =
            *(const uint4*)(Kg + (size_t)(bh * SEQ + r) * DHEAD + kd);
    }
    uint4 kpre[4];
    if constexpr (NPH == 2) {            // issue ph1 K loads early
#pragma unroll
        for (int it = 0; it < R1 / 32; ++it) {
            const int r = it * 32 + kr;
            kpre[it] = *(const uint4*)(Kg + (size_t)(bh * SEQ + 128 + r) * DHEAD + kd);
        }
    }
    __syncthreads();

    // compute ph0 (ph1 K loads in flight underneath)
#pragma unroll
    for (int t = 0; t < R0 / 16; ++t) {
        const int gt = t;
        if (gt * 16 <= qmax) {
            f32x4 z = {0.f, 0.f, 0.f, 0.f};
#pragma unroll
            for (int ks = 0; ks < 2; ++ks) {
                short8 bk = *(const short8*)(Kbuf + (t * 16 + l15) * 72
                                             + ks * 32 + q4 * 8);
                z = mfma16(aq[ks], bk, z);
            }
            const int kc = gt * 16 + l15;
#pragma unroll
            for (int r = 0; r < 4; ++r) {
                float v = z[r] * SCALE;
                if (kc > qrow0 + q4 * 4 + r) v = -1e30f;
                z[r] = v;
            }
            s[gt] = z;
        } else {
            f32x4 neg = {-1e30f, -1e30f, -1e30f, -1e30f};
            s[gt] = neg;
        }
    }

    if constexpr (NPH == 2) {
        __syncthreads();                 // all waves done reading Kbuf ph0
#pragma unroll
        for (int it = 0; it < R1 / 32; ++it) {
            const int r = it * 32 + kr;
            *(uint4*)(Kbuf + r * 72 + kd) = kpre[it];
        }
        __syncthreads();
#pragma unroll
        for (int t = 0; t < R1 / 16; ++t) {
            const int gt = 8 + t;
            if (gt * 16 <= qmax) {
                f32x4 z = {0.f, 0.f, 0.f, 0.f};
#pragma unroll
                for (int ks = 0; ks < 2; ++ks) {
                    short8 bk = *(const short8*)(Kbuf + (t * 16 + l15) * 72
                                                 + ks * 32 + q4 * 8);
                    z = mfma16(aq[ks], bk, z);
                }
                const int kc = gt * 16 + l15;
#pragma unroll
                for (int r = 0; r < 4; ++r) {
                    float v = z[r] * SCALE;
                    if (kc > qrow0 + q4 * 4 + r) v = -1e30f;
                    z[r] = v;
                }
                s[gt] = z;
            } else {
                f32x4 neg = {-1e30f, -1e30f, -1e30f, -1e30f};
                s[gt] = neg;
            }
        }
    }
    __syncthreads();   // S done; Kbuf free for Vt overwrite later

    // ---- issue ph0 V loads (latency hides under softmax) ----------------
    constexpr int C0  = R0 >> 3;         // uint4 chunks per d-row, ph0
    constexpr int NV0 = (64 * C0) / 256; // per-thread uint4 (2 or 4)
    uint4 va[4];
#pragma unroll
    for (int it = 0; it < NV0; ++it) {
        const int flat = it * 256 + tid;
        const int rd = flat / C0;
        const int kc = (flat - rd * C0) * 8;
        va[it] = *(const uint4*)(VTg + ((size_t)bh * DHEAD + rd) * SEQ + kc);
    }

    // ---- softmax --------------------------------------------------------
    float mx[4], sm[4], rs[4];
#pragma unroll
    for (int r = 0; r < 4; ++r) {
        float m = -1e30f;
#pragma unroll
        for (int t = 0; t < KT; ++t) m = fmaxf(m, s[t][r]);
#pragma unroll
        for (int off = 1; off < 16; off <<= 1)
            m = fmaxf(m, __shfl_xor(m, off, 16));
        mx[r] = m;
        sm[r] = 0.f;
    }
#pragma unroll
    for (int t = 0; t < KT; ++t)
#pragma unroll
        for (int r = 0; r < 4; ++r) {
            float p = __expf(s[t][r] - mx[r]);
            s[t][r] = p;
            sm[r] += p;
        }
#pragma unroll
    for (int r = 0; r < 4; ++r) {
#pragma unroll
        for (int off = 1; off < 16; off <<= 1)
            sm[r] += __shfl_xor(sm[r], off, 16);
        rs[r] = 1.f / sm[r];
    }

    // ---- bulk P write (per-wave panel) ----------------------------------
#pragma unroll
    for (int gt = 0; gt < KT; ++gt)
#pragma unroll
        for (int r = 0; r < 4; ++r)
            Pl[(q4 * 4 + r) * PLD + gt * 16 + l15] = f2b(s[gt][r]);

    // ---- write ph0 V into Vt; issue ph1 V loads -------------------------
    u16* Vt = SA;                        // [64 d][136] (Kbuf dead)
#pragma unroll
    for (int it = 0; it < NV0; ++it) {
        const int flat = it * 256 + tid;
        const int rd = flat / C0;
        const int kc = (flat - rd * C0) * 8;
        *(uint4*)(Vt + rd * 136 + kc) = va[it];
    }
    constexpr int C1  = (R1 > 0) ? (R1 >> 3) : 8;
    constexpr int NV1 = (R1 > 0) ? (64 * (R1 >> 3)) / 256 : 0;
    uint4 vb[4];
    if constexpr (NPH == 2) {            // issue ph1 V loads early
#pragma unroll
        for (int it = 0; it < NV1; ++it) {
            const int flat = it * 256 + tid;
            const int rd = flat / C1;
            const int kc = (flat - rd * C1) * 8;
            vb[it] = *(const uint4*)(VTg + ((size_t)bh * DHEAD + rd) * SEQ
                                         + 128 + kc);
        }
    }
    __syncthreads();   // Vt ph0 + P writes visible (drains lgkmcnt)

    // ---- PV ph0 (ph1 V loads in flight underneath) ----------------------
    f32x4 o[4] = {};
#pragma unroll
    for (int ks = 0; ks < R0 / 32; ++ks) {
        const int gks = ks;
        if (gks * 32 <= qmax) {
            short8 ap = *(const short8*)(Pl + l15 * PLD + gks * 32 + q4 * 8);
#pragma unroll
            for (int tn = 0; tn < 4; ++tn) {
                short8 bv = *(const short8*)(Vt + (tn * 16 + l15) * 136
                                             + ks * 32 + q4 * 8);
                o[tn] = mfma16(ap, bv, o[tn]);
            }
        }
    }
    if constexpr (NPH == 2) {
        __syncthreads();                 // all done reading Vt ph0
#pragma unroll
        for (int it = 0; it < NV1; ++it) {
            const int flat = it * 256 + tid;
            const int rd = flat / C1;
            const int kc = (flat - rd * C1) * 8;
            *(uint4*)(Vt + rd * 136 + kc) = vb[it];
        }
        __syncthreads();
#pragma unroll
        for (int ks = 0; ks < R1 / 32; ++ks) {
            const int gks = 4 + ks;
            if (gks * 32 <= qmax) {
                short8 ap = *(const short8*)(Pl + l15 * PLD + gks * 32 + q4 * 8);
#pragma unroll
                for (int tn = 0; tn < 4; ++tn) {
                    short8 bv = *(const short8*)(Vt + (tn * 16 + l15) * 136
                                                 + ks * 32 + q4 * 8);
                    o[tn] = mfma16(ap, bv, o[tn]);
                }
            }
        }
    }
    __syncthreads();   // all done reading Vt before OL overwrite

    // ---- store O -> ws [NROW][CDIM] bf16, coalesced via LDS -------------
    u16* OL = SA;                        // [64 q][64 d], XOR chunk-swz
#pragma unroll
    for (int tn = 0; tn < 4; ++tn) {
        const int col = tn * 16 + l15;
#pragma unroll
        for (int r = 0; r < 4; ++r) {
            const int row = wv * 16 + q4 * 4 + r;
            OL[row * 64 + (((col >> 3) ^ (row & 7)) << 3) + (col & 7)] =
                f2b(o[tn][r] * rs[r]);
        }
    }
    __syncthreads();
    const int b  = bh / NHEAD;
    const int h  = bh - b * NHEAD;
    const int seg0 = tid >> 3;           // 0..31
    const int c    = tid & 7;
#pragma unroll
    for (int it = 0; it < 2; ++it) {
        const int row = it * 32 + seg0;  // 0..63
        const int chunk = c ^ (row & 7);
        *(uint4*)(Og + (size_t)(b * SEQ + CH * 64 + row) * CDIM
                     + h * DHEAD + c * 8) =
            *(const uint4*)(OL + row * 64 + chunk * 8);
    }
}

__global__ __launch_bounds__(256) void attn_kernel(
        const u16* __restrict__ Qg, const u16* __restrict__ Kg,
        const u16* __restrict__ VTg, u16* __restrict__ Og)
{
    __shared__ u16 SA[128 * 72];        // 18 KB, phase-aliased (Kbuf/Vt/OL)
    __shared__ u16 Pls[4 * 16 * PLD];   // 33 KB, per-wave P panels
    // XCD-bijective decode: 1536 = 8 XCD x 48 bh x 4 chunks
    const int bid = blockIdx.x;
    const int xcd = bid & 7;
    const int g   = bid >> 3;            // 0..191
    const int bh  = xcd * 48 + (g >> 2);
    const int ch  = g & 3;
    switch (ch) {
        case 0: attn_body<0>(Qg, Kg, VTg, Og, bh, SA, Pls); break;
        case 1: attn_body<1>(Qg, Kg, VTg, Og, bh, SA, Pls); break;
        case 2: attn_body<2>(Qg, Kg, VTg, Og, bh, SA, Pls); break;
        default: attn_body<3>(Qg, Kg, VTg, Og, bh, SA, Pls); break;
    }
}

// ---------------------------------------------------------------------------
// Output projection (bf16 inputs): out = O @ Wo^T + bo. O bf16 [NROW][CDIM],
// Wo bf16, bo fp32. 64x128 tile, BK=64. 2-phase pipeline (same transform as
// gemm_qkv): double-buffered LDS (2 x 24 KB), raw s_barrier + vmcnt(6).
// XCD swizzle: 768 = 8 XCD x 32 m x 3 n, bijective. Writes fp32 [16384x384].
// ---------------------------------------------------------------------------
__global__ __launch_bounds__(256) void gemm_out(
        const u16* __restrict__ O, const u16* __restrict__ Wo,
        const float* __restrict__ bias, float* __restrict__ out)
{
    __shared__ u16 SMEM[24576];   // 48 KB: buf b at b*12288 = [As 4096 | Bs 8192]

    const int bid = blockIdx.x;
    const int xcd = bid & 7;
    const int g   = bid >> 3;            // 0..95
    const int mt  = xcd * 32 + g / 3;    // 0..255
    const int n0  = (g % 3) * 128;
    const int m0  = mt * 64;

    const int tid  = threadIdx.x;
    const int lane = tid & 63;
    const int wv   = tid >> 6;
    const int l15  = lane & 15;
    const int q4   = lane >> 4;
    const int wm   = (wv >> 1) * 32;
    const int wn   = (wv & 1) * 64;

    f32x4 acc[2][4] = {};

    auto STAGE = [&](int kk, int buf) {
#pragma unroll
        for (int ch = 0; ch < 4; ++ch) {
            const int f = (ch * 256 + tid) * 8;
            const int r = f >> 6;
            const int c = (f ^ ((r & 7) << 3)) & 63;
            const int lb = (ch * 256 + wv * 64) * 8;
            gload_lds16(Wo + (size_t)(n0 + r) * CDIM + kk + c,
                        SMEM + buf * 12288 + 4096 + lb);
            if (ch < 2)
                gload_lds16(O + (size_t)(m0 + r) * CDIM + kk + c,
                            SMEM + buf * 12288 + lb);
        }
    };

    STAGE(0, 0);
#pragma unroll
    for (int t = 0; t < 6; ++t) {
        const int cur = t & 1;
        if (t < 5) {
            STAGE((t + 1) * 64, cur ^ 1);
            asm volatile("s_waitcnt vmcnt(6)" ::: "memory");  // tile t's 6 done
        } else {
            asm volatile("s_waitcnt vmcnt(0)" ::: "memory");
        }
        asm volatile("s_barrier" ::: "memory");

        const u16* As = SMEM + cur * 12288;
        const u16* Bs = SMEM + cur * 12288 + 4096;
#pragma unroll
        for (int ks = 0; ks < 2; ++ks) {
            short8 af[2], bf[4];
#pragma unroll
            for (int tt = 0; tt < 2; ++tt) {
                const int ra = wm + tt * 16 + l15;
                af[tt] = *(const short8*)(As + ra * 64 +
                        ((ks * 32 + q4 * 8) ^ ((ra & 7) << 3)));
            }
#pragma unroll
            for (int tt = 0; tt < 4; ++tt) {
                const int rb = wn + tt * 16 + l15;
                bf[tt] = *(const short8*)(Bs + rb * 64 +
                        ((ks * 32 + q4 * 8) ^ ((rb & 7) << 3)));
            }
#pragma unroll
            for (int tm = 0; tm < 2; ++tm)
#pragma unroll
                for (int tn = 0; tn < 4; ++tn)
                    acc[tm][tn] = mfma16(af[tm], bf[tn], acc[tm][tn]);
        }
        asm volatile("s_barrier" ::: "memory");
    }

#pragma unroll
    for (int tm = 0; tm < 2; ++tm) {
#pragma unroll
        for (int tn = 0; tn < 4; ++tn) {
            const int col = n0 + wn + tn * 16 + l15;
            const float bb = bias[col];
#pragma unroll
            for (int r = 0; r < 4; ++r) {
                const int row = m0 + wm + tm * 16 + q4 * 4 + r;
                out[(size_t)row * CDIM + col] = acc[tm][tn][r] + bb;  // fp32
            }
        }
    }
}

extern "C" void kernel_launch(void* const* d_in, const int* in_sizes, int n_in,
                              void* d_out, int out_size, void* d_ws, size_t ws_size,
                              hipStream_t stream)
{
    const float* x  = (const float*)d_in[0];
    const float* Wk = (const float*)d_in[1];
    const float* Wq = (const float*)d_in[2];
    const float* Wv = (const float*)d_in[3];
    const float* Wo = (const float*)d_in[4];
    const float* bo = (const float*)d_in[5];
    float* out = (float*)d_out;

    // ws layout (u16): xb + 4 weights + K + Q + O  = 51.5 MB
    const size_t SZ = (size_t)NROW * CDIM;   // 6,291,456
    const size_t WZ = (size_t)CDIM * CDIM;   //   147,456
    u16* xb  = (u16*)d_ws;
    u16* Wkb = xb  + SZ;
    u16* Wqb = Wkb + WZ;
    u16* Wvb = Wqb + WZ;
    u16* Wob = Wvb + WZ;
    u16* Kw  = Wob + WZ;
    u16* Qw  = Kw + SZ;
    u16* Ow  = Qw + SZ;
    u16* VTw = (u16*)d_out;   // V^T [B,H,D,T] scratch in d_out

    cvt_all<<<dim3(3360), 256, 0, stream>>>(
        x, Wk, Wq, Wv, Wo, xb, Wkb, Wqb, Wvb, Wob);

    gemm_qkv<<<dim3(1152), 256, 0, stream>>>(xb, Wkb, Wvb, Wqb, Kw, VTw, Qw);

    attn_kernel<<<dim3(1536), 256, 0, stream>>>(Qw, Kw, VTw, Ow);

    gemm_out<<<dim3(768), 256, 0, stream>>>(Ow, Wob, bo, out);
}

// Round 11
// 137.194 us; speedup vs baseline: 1.0974x; 1.0974x over previous
//
#include <hip/hip_runtime.h>
#include <hip/hip_bf16.h>

typedef unsigned short u16;
typedef __attribute__((ext_vector_type(8))) short short8;   // 8 bf16 = 4 VGPRs
typedef __attribute__((ext_vector_type(4))) float f32x4;

#define BATCH 64
#define SEQ   256
#define CDIM  384
#define NHEAD 6
#define DHEAD 64
#define NROW  16384   // BATCH*SEQ

constexpr float SCALE = 0.051031036307982884f;  // 384^-0.5

__device__ __forceinline__ f32x4 mfma16(short8 a, short8 b, f32x4 c) {
    return __builtin_amdgcn_mfma_f32_16x16x32_bf16(a, b, c, 0, 0, 0);
}

__device__ __forceinline__ u16 f2b(float f) {
    __hip_bfloat16 h = __float2bfloat16(f);
    return *reinterpret_cast<u16*>(&h);
}

__device__ __forceinline__ void gload_lds16(const u16* g, u16* l) {
    __builtin_amdgcn_global_load_lds(
        (const __attribute__((address_space(1))) void*)g,
        (__attribute__((address_space(3))) void*)l, 16, 0, 0);
}

// ---------------------------------------------------------------------------
// fp32 -> bf16 conversion for x AND the 4 weights, one launch.
// blocks [0,3072): x (6291456 elems); [3072,3360): weights, 72 blocks each.
// ---------------------------------------------------------------------------
__global__ __launch_bounds__(256) void cvt_all(
        const float* __restrict__ x,
        const float* __restrict__ Wk, const float* __restrict__ Wq,
        const float* __restrict__ Wv, const float* __restrict__ Wo,
        u16* __restrict__ xb,
        u16* __restrict__ wkb, u16* __restrict__ wqb,
        u16* __restrict__ wvb, u16* __restrict__ wob)
{
    int blk = blockIdx.x;
    const float* s;
    u16* d;
    if (blk < 3072) {
        s = x; d = xb;
    } else {
        const int w = blk - 3072;
        const int z = w / 72;           // 0..3
        blk = w - z * 72;
        s = (z == 0) ? Wk : (z == 1) ? Wq : (z == 2) ? Wv : Wo;
        d = (z == 0) ? wkb : (z == 1) ? wqb : (z == 2) ? wvb : wob;
    }
    const int i = (blk * 256 + (int)threadIdx.x) * 8;
    const float4 a = *(const float4*)(s + i);
    const float4 b = *(const float4*)(s + i + 4);
    short8 r;
    r[0] = (short)f2b(a.x); r[1] = (short)f2b(a.y);
    r[2] = (short)f2b(a.z); r[3] = (short)f2b(a.w);
    r[4] = (short)f2b(b.x); r[5] = (short)f2b(b.y);
    r[6] = (short)f2b(b.z); r[7] = (short)f2b(b.w);
    *(short8*)(d + i) = r;
}

// ---------------------------------------------------------------------------
// QKV projection (all-bf16): Y = X @ W^T. 128x128 tile, BK=64, 4 waves @
// 64x64. 2-phase pipeline: double-buffered LDS, raw s_barrier + counted
// vmcnt(8) (proven R9). XCD swizzle: 1152 = 8 x 16 panels x 9 sharers.
//   z=0: K -> ws  [B,H,T,D]    z=1: V -> d_out [B,H,D,T] (transposed)
//   z=2: Q -> ws  [B,H,T,D]
// ---------------------------------------------------------------------------
__global__ __launch_bounds__(256) void gemm_qkv(
        const u16* __restrict__ X, const u16* __restrict__ Wk,
        const u16* __restrict__ Wv, const u16* __restrict__ Wq,
        u16* __restrict__ Kd, u16* __restrict__ VTd, u16* __restrict__ Qd)
{
    __shared__ u16 SMEM[32768];   // 64 KB: buf b = [As 8192 | Bs 8192] at b*16384

    const int bid   = blockIdx.x;        // 0..1151
    const int xcd   = bid & 7;
    const int i     = bid >> 3;          // 0..143
    const int igrp  = i / 9;             // 0..15
    const int j     = i - igrp * 9;      // 0..8
    const int panel = xcd * 16 + igrp;   // 0..127
    const int m0    = panel * 128;
    const int n0    = (j % 3) * 128;
    const int z     = j / 3;
    const u16* W = (z == 0) ? Wk : (z == 1 ? Wv : Wq);

    const int tid  = threadIdx.x;
    const int lane = tid & 63;
    const int wv   = tid >> 6;
    const int l15  = lane & 15;
    const int q4   = lane >> 4;
    const int wm   = (wv >> 1) * 64;
    const int wn   = (wv & 1) * 64;

    f32x4 acc[4][4] = {};

    auto STAGE = [&](int kk, int buf) {
#pragma unroll
        for (int ch = 0; ch < 4; ++ch) {
            const int f  = (ch * 256 + tid) * 8;
            const int r  = f >> 6;
            const int cb = (f ^ ((r & 7) << 3)) & 63;   // inverse-swizzled col
            const int lb = buf * 16384 + (ch * 256 + wv * 64) * 8;
            gload_lds16(X + (size_t)(m0 + r) * CDIM + kk + cb, SMEM + lb);
            gload_lds16(W + (size_t)(n0 + r) * CDIM + kk + cb, SMEM + 8192 + lb);
        }
    };

    STAGE(0, 0);
#pragma unroll
    for (int t = 0; t < 6; ++t) {
        const int cur = t & 1;
        if (t < 5) {
            STAGE((t + 1) * 64, cur ^ 1);
            asm volatile("s_waitcnt vmcnt(8)" ::: "memory");  // tile t's 8 done
        } else {
            asm volatile("s_waitcnt vmcnt(0)" ::: "memory");
        }
        asm volatile("s_barrier" ::: "memory");   // tile t visible, prefetch live

        const u16* As = SMEM + cur * 16384;
        const u16* Bs = SMEM + cur * 16384 + 8192;
#pragma unroll
        for (int ks = 0; ks < 2; ++ks) {
            short8 af[4], bf[4];
#pragma unroll
            for (int tt = 0; tt < 4; ++tt) {
                const int ra = wm + tt * 16 + l15;
                const int rb = wn + tt * 16 + l15;
                af[tt] = *(const short8*)(As + ra * 64 +
                        ((ks * 32 + q4 * 8) ^ ((ra & 7) << 3)));
                bf[tt] = *(const short8*)(Bs + rb * 64 +
                        ((ks * 32 + q4 * 8) ^ ((rb & 7) << 3)));
            }
#pragma unroll
            for (int tm = 0; tm < 4; ++tm)
#pragma unroll
                for (int tn = 0; tn < 4; ++tn)
                    acc[tm][tn] = mfma16(af[tm], bf[tn], acc[tm][tn]);
        }
        asm volatile("s_barrier" ::: "memory");   // buf free for next overwrite
    }

    if (z != 1) {
        // ---- coalesced epilogue to [B,H,T,D] via LDS --------------------
        u16* D = (z == 0) ? Kd : Qd;
        u16* T = SMEM;                    // [128 t][128 col], XOR chunk-swz
#pragma unroll
        for (int tm = 0; tm < 4; ++tm)
#pragma unroll
            for (int tn = 0; tn < 4; ++tn) {
                const int cl = wn + tn * 16 + l15;
#pragma unroll
                for (int r = 0; r < 4; ++r) {
                    const int row = wm + tm * 16 + q4 * 4 + r;
                    T[row * 128 + (((cl >> 3) ^ (row & 7)) << 3) + (cl & 7)] =
                        f2b(acc[tm][tn][r]);
                }
            }
        __syncthreads();
        const int seg0 = tid >> 3;        // 0..31
        const int c    = tid & 7;         // 16B chunk within 64-d segment
#pragma unroll
        for (int it = 0; it < 8; ++it) {
            const int S   = it * 32 + seg0;   // 0..255: (row, head-half)
            const int row = S >> 1;
            const int hf  = S & 1;
            const int rowg = m0 + row;
            const int b  = rowg >> 8, tt = rowg & 255;
            const int h  = (n0 + hf * 64) >> 6;
            const int chunk = (hf * 8 + c) ^ (row & 7);
            *(uint4*)(D + (size_t)((b * NHEAD + h) * SEQ + tt) * DHEAD + c * 8) =
                *(const uint4*)(T + row * 128 + chunk * 8);
        }
    } else {
        // ---- transpose epilogue: V^T [B,H,D,T] --------------------------
        u16* T = SMEM;                    // [128 feat][136]
#pragma unroll
        for (int tm = 0; tm < 4; ++tm)
#pragma unroll
            for (int tn = 0; tn < 4; ++tn) {
                const int cl = wn + tn * 16 + l15;            // feature-local
#pragma unroll
                for (int r = 0; r < 4; ++r) {
                    const int rl = wm + tm * 16 + q4 * 4 + r; // t-local
                    T[cl * 136 + rl] = f2b(acc[tm][tn][r]);
                }
            }
        __syncthreads();
        const int b  = m0 >> 8;
        const int t0 = m0 & 255;
        const int fl = tid >> 1;          // feature-local 0..127
        const int hf = tid & 1;           // which 64-t half
        const int fg = n0 + fl;
        const int h  = fg >> 6, d = fg & 63;
        u16* dst = VTd + ((size_t)(b * NHEAD + h) * DHEAD + d) * SEQ + t0 + hf * 64;
        const u16* src = T + fl * 136 + hf * 64;
#pragma unroll
        for (int j2 = 0; j2 < 8; ++j2)
            *(uint4*)(dst + j2 * 8) = *(const uint4*)(src + j2 * 8);
    }
}

// ---------------------------------------------------------------------------
// Attention: 64 query rows per block, causal keys [0,64(CH+1)).
// HALF-SIZED per-wave P panel [16][136]: P is wave-private (same wave writes
// and reads it -> no cross-wave sync), and PV consumes keys in 128-wide
// phases, so the panel is filled per phase (half1 overwrites half0 after
// PV-ph0's reads; same-wave LDS ordering makes this safe). LDS 51->36 KB ->
// 4 blocks/CU (enforced via __launch_bounds__(256,4)).
// XCD swizzle: all 4 chunk-blocks of one bh on ONE XCD (K/V L2-local).
// O written row-major [NROW][CDIM] bf16 (coalesced uint4 via LDS).
// ---------------------------------------------------------------------------
#define PLD 136   // P half-panel leading dim (u16): 128 keys + 8 pad

template <int CH>
__device__ __forceinline__ void attn_body(
        const u16* __restrict__ Qg, const u16* __restrict__ Kg,
        const u16* __restrict__ VTg, u16* __restrict__ Og, int bh,
        u16* SA, u16* Pbase)
{
    constexpr int NKEY = 64 * (CH + 1);
    constexpr int KT   = NKEY / 16;
    constexpr int NPH  = (NKEY + 127) / 128;
    constexpr int R0   = (NKEY < 128) ? NKEY : 128;   // keys in phase 0
    constexpr int R1   = NKEY - R0;                   // keys in phase 1

    const int tid  = threadIdx.x;
    const int wv   = tid >> 6;
    const int lane = tid & 63;
    const int l15  = lane & 15;
    const int q4   = lane >> 4;
    const int qrow0 = CH * 64 + wv * 16;
    const int qmax  = qrow0 + 15;
    u16* Pl = Pbase + wv * 16 * PLD;     // per-wave P half-panel [16 q][PLD]

    short8 aq[2];
#pragma unroll
    for (int ks = 0; ks < 2; ++ks)
        aq[ks] = *(const short8*)(Qg + (size_t)(bh * SEQ + qrow0 + l15) * DHEAD
                                     + ks * 32 + q4 * 8);

    // ---- S = Q K^T * scale, causal --------------------------------------
    u16* Kbuf = SA;                      // [128][72]
    f32x4 s[KT];
#pragma unroll
    for (int ph = 0; ph < NPH; ++ph) {
        const int rows = (NKEY - ph * 128) < 128 ? (NKEY - ph * 128) : 128;
        for (int it = 0; it < rows / 32; ++it) {
            const int r  = it * 32 + (tid >> 3);
            const int d0 = (tid & 7) * 8;
            *(uint4*)(Kbuf + r * 72 + d0) =
                *(const uint4*)(Kg + (size_t)(bh * SEQ + ph * 128 + r) * DHEAD + d0);
        }
        __syncthreads();
#pragma unroll
        for (int t = 0; t < rows / 16; ++t) {
            const int gt = ph * 8 + t;
            if (gt * 16 <= qmax) {
                f32x4 z = {0.f, 0.f, 0.f, 0.f};
#pragma unroll
                for (int ks = 0; ks < 2; ++ks) {
                    short8 bk = *(const short8*)(Kbuf + (t * 16 + l15) * 72
                                                 + ks * 32 + q4 * 8);
                    z = mfma16(aq[ks], bk, z);
                }
                const int kc = gt * 16 + l15;
#pragma unroll
                for (int r = 0; r < 4; ++r) {
                    float v = z[r] * SCALE;
                    if (kc > qrow0 + q4 * 4 + r) v = -1e30f;
                    z[r] = v;
                }
                s[gt] = z;
            } else {
                f32x4 neg = {-1e30f, -1e30f, -1e30f, -1e30f};
                s[gt] = neg;
            }
        }
        __syncthreads();
    }

    // ---- softmax --------------------------------------------------------
    float mx[4], sm[4], rs[4];
#pragma unroll
    for (int r = 0; r < 4; ++r) {
        float m = -1e30f;
#pragma unroll
        for (int t = 0; t < KT; ++t) m = fmaxf(m, s[t][r]);
#pragma unroll
        for (int off = 1; off < 16; off <<= 1)
            m = fmaxf(m, __shfl_xor(m, off, 16));
        mx[r] = m;
        sm[r] = 0.f;
    }
#pragma unroll
    for (int t = 0; t < KT; ++t)
#pragma unroll
        for (int r = 0; r < 4; ++r) {
            float p = __expf(s[t][r] - mx[r]);
            s[t][r] = p;
            sm[r] += p;
        }
#pragma unroll
    for (int r = 0; r < 4; ++r) {
#pragma unroll
        for (int off = 1; off < 16; off <<= 1)
            sm[r] += __shfl_xor(sm[r], off, 16);
        rs[r] = 1.f / sm[r];
    }

    // ---- O = P V: per-phase Vt staging + per-phase P half-panel ---------
    u16* Vt = SA;                        // [64 d][136] (Kbuf dead)
    f32x4 o[4] = {};

    // phase 0: stage Vt[.., keys 0..R0)
    constexpr int C0  = R0 >> 3;         // uint4 chunks per d-row
    constexpr int NV0 = (64 * C0) / 256; // per-thread uint4
#pragma unroll
    for (int it = 0; it < NV0; ++it) {
        const int flat = it * 256 + tid;
        const int rd = flat / C0;
        const int kc = (flat - rd * C0) * 8;
        *(uint4*)(Vt + rd * 136 + kc) =
            *(const uint4*)(VTg + ((size_t)bh * DHEAD + rd) * SEQ + kc);
    }
    // write P half0 (wave-private; visibility via the barrier below)
#pragma unroll
    for (int gt = 0; gt < R0 / 16; ++gt)
#pragma unroll
        for (int r = 0; r < 4; ++r)
            Pl[(q4 * 4 + r) * PLD + gt * 16 + l15] = f2b(s[gt][r]);
    __syncthreads();   // Vt ph0 visible (drains vmcnt+lgkmcnt)

#pragma unroll
    for (int ks = 0; ks < R0 / 32; ++ks) {
        if (ks * 32 <= qmax) {
            short8 ap = *(const short8*)(Pl + l15 * PLD + ks * 32 + q4 * 8);
#pragma unroll
            for (int tn = 0; tn < 4; ++tn) {
                short8 bv = *(const short8*)(Vt + (tn * 16 + l15) * 136
                                             + ks * 32 + q4 * 8);
                o[tn] = mfma16(ap, bv, o[tn]);
            }
        }
    }

    if constexpr (NPH == 2) {
        __syncthreads();                 // all waves done reading Vt ph0
        // stage Vt[.., keys 128..NKEY)
        constexpr int C1  = R1 >> 3;
        constexpr int NV1 = (64 * C1) / 256;
#pragma unroll
        for (int it = 0; it < NV1; ++it) {
            const int flat = it * 256 + tid;
            const int rd = flat / C1;
            const int kc = (flat - rd * C1) * 8;
            *(uint4*)(Vt + rd * 136 + kc) =
                *(const uint4*)(VTg + ((size_t)bh * DHEAD + rd) * SEQ + 128 + kc);
        }
        // overwrite P panel with half1 (same wave already consumed half0)
#pragma unroll
        for (int gt = 8; gt < KT; ++gt)
#pragma unroll
            for (int r = 0; r < 4; ++r)
                Pl[(q4 * 4 + r) * PLD + (gt - 8) * 16 + l15] = f2b(s[gt][r]);
        __syncthreads();                 // Vt ph1 visible

#pragma unroll
        for (int ks = 0; ks < R1 / 32; ++ks) {
            const int gks = 4 + ks;
            if (gks * 32 <= qmax) {
                short8 ap = *(const short8*)(Pl + l15 * PLD + ks * 32 + q4 * 8);
#pragma unroll
                for (int tn = 0; tn < 4; ++tn) {
                    short8 bv = *(const short8*)(Vt + (tn * 16 + l15) * 136
                                                 + ks * 32 + q4 * 8);
                    o[tn] = mfma16(ap, bv, o[tn]);
                }
            }
        }
    }
    __syncthreads();   // all done reading Vt before OL overwrite

    // ---- store O -> ws [NROW][CDIM] bf16, coalesced via LDS -------------
    u16* OL = SA;                        // [64 q][64 d], XOR chunk-swz
#pragma unroll
    for (int tn = 0; tn < 4; ++tn) {
        const int col = tn * 16 + l15;
#pragma unroll
        for (int r = 0; r < 4; ++r) {
            const int row = wv * 16 + q4 * 4 + r;
            OL[row * 64 + (((col >> 3) ^ (row & 7)) << 3) + (col & 7)] =
                f2b(o[tn][r] * rs[r]);
        }
    }
    __syncthreads();
    const int b  = bh / NHEAD;
    const int h  = bh - b * NHEAD;
    const int seg0 = tid >> 3;           // 0..31
    const int c    = tid & 7;
#pragma unroll
    for (int it = 0; it < 2; ++it) {
        const int row = it * 32 + seg0;  // 0..63
        const int chunk = c ^ (row & 7);
        *(uint4*)(Og + (size_t)(b * SEQ + CH * 64 + row) * CDIM
                     + h * DHEAD + c * 8) =
            *(const uint4*)(OL + row * 64 + chunk * 8);
    }
}

__global__ __launch_bounds__(256, 4) void attn_kernel(
        const u16* __restrict__ Qg, const u16* __restrict__ Kg,
        const u16* __restrict__ VTg, u16* __restrict__ Og)
{
    __shared__ u16 SA[128 * 72];        // 18 KB, phase-aliased (Kbuf/Vt/OL)
    __shared__ u16 Pls[4 * 16 * PLD];   // 17 KB, per-wave P half-panels
    // XCD-bijective decode: 1536 = 8 XCD x 48 bh x 4 chunks
    const int bid = blockIdx.x;
    const int xcd = bid & 7;
    const int g   = bid >> 3;            // 0..191
    const int bh  = xcd * 48 + (g >> 2);
    const int ch  = g & 3;
    switch (ch) {
        case 0: attn_body<0>(Qg, Kg, VTg, Og, bh, SA, Pls); break;
        case 1: attn_body<1>(Qg, Kg, VTg, Og, bh, SA, Pls); break;
        case 2: attn_body<2>(Qg, Kg, VTg, Og, bh, SA, Pls); break;
        default: attn_body<3>(Qg, Kg, VTg, Og, bh, SA, Pls); break;
    }
}

// ---------------------------------------------------------------------------
// Output projection (bf16 inputs): out = O @ Wo^T + bo. O bf16 [NROW][CDIM]
// row-major (linear global_load_lds staging), Wo bf16, bo fp32.
// 64x128 tile, BK=64, XOR-swizzled LDS (R9 version: single-buffer, 24 KB,
// 6 blocks/CU — R10 showed the dbuf/occupancy trade loses here).
// XCD swizzle: 768 = 8 XCD x 32 m x 3 n, bijective. Writes fp32 [16384x384].
// ---------------------------------------------------------------------------
__global__ __launch_bounds__(256) void gemm_out(
        const u16* __restrict__ O, const u16* __restrict__ Wo,
        const float* __restrict__ bias, float* __restrict__ out)
{
    __shared__ u16 As[64 * 64];    //  8 KB
    __shared__ u16 Bs[128 * 64];   // 16 KB

    const int bid = blockIdx.x;
    const int xcd = bid & 7;
    const int g   = bid >> 3;            // 0..95
    const int mt  = xcd * 32 + g / 3;    // 0..255
    const int n0  = (g % 3) * 128;
    const int m0  = mt * 64;

    const int tid  = threadIdx.x;
    const int lane = tid & 63;
    const int wv   = tid >> 6;
    const int l15  = lane & 15;
    const int q4   = lane >> 4;
    const int wm   = (wv >> 1) * 32;
    const int wn   = (wv & 1) * 64;

    f32x4 acc[2][4] = {};

    for (int kk = 0; kk < CDIM; kk += 64) {
        __syncthreads();
#pragma unroll
        for (int ch = 0; ch < 4; ++ch) {
            const int f = (ch * 256 + tid) * 8;
            const int r = f >> 6;
            const int c = (f ^ ((r & 7) << 3)) & 63;
            const int lb = (ch * 256 + wv * 64) * 8;
            gload_lds16(Wo + (size_t)(n0 + r) * CDIM + kk + c, Bs + lb);
            if (ch < 2)
                gload_lds16(O + (size_t)(m0 + r) * CDIM + kk + c, As + lb);
        }
        __syncthreads();

#pragma unroll
        for (int ks = 0; ks < 2; ++ks) {
            short8 af[2], bf[4];
#pragma unroll
            for (int t = 0; t < 2; ++t) {
                const int ra = wm + t * 16 + l15;
                af[t] = *(const short8*)(As + ra * 64 +
                        ((ks * 32 + q4 * 8) ^ ((ra & 7) << 3)));
            }
#pragma unroll
            for (int t = 0; t < 4; ++t) {
                const int rb = wn + t * 16 + l15;
                bf[t] = *(const short8*)(Bs + rb * 64 +
                        ((ks * 32 + q4 * 8) ^ ((rb & 7) << 3)));
            }
#pragma unroll
            for (int tm = 0; tm < 2; ++tm)
#pragma unroll
                for (int tn = 0; tn < 4; ++tn)
                    acc[tm][tn] = mfma16(af[tm], bf[tn], acc[tm][tn]);
        }
    }

#pragma unroll
    for (int tm = 0; tm < 2; ++tm) {
#pragma unroll
        for (int tn = 0; tn < 4; ++tn) {
            const int col = n0 + wn + tn * 16 + l15;
            const float bb = bias[col];
#pragma unroll
            for (int r = 0; r < 4; ++r) {
                const int row = m0 + wm + tm * 16 + q4 * 4 + r;
                out[(size_t)row * CDIM + col] = acc[tm][tn][r] + bb;  // fp32
            }
        }
    }
}

extern "C" void kernel_launch(void* const* d_in, const int* in_sizes, int n_in,
                              void* d_out, int out_size, void* d_ws, size_t ws_size,
                              hipStream_t stream)
{
    const float* x  = (const float*)d_in[0];
    const float* Wk = (const float*)d_in[1];
    const float* Wq = (const float*)d_in[2];
    const float* Wv = (const float*)d_in[3];
    const float* Wo = (const float*)d_in[4];
    const float* bo = (const float*)d_in[5];
    float* out = (float*)d_out;

    // ws layout (u16): xb + 4 weights + K + Q + O  = 51.5 MB
    const size_t SZ = (size_t)NROW * CDIM;   // 6,291,456
    const size_t WZ = (size_t)CDIM * CDIM;   //   147,456
    u16* xb  = (u16*)d_ws;
    u16* Wkb = xb  + SZ;
    u16* Wqb = Wkb + WZ;
    u16* Wvb = Wqb + WZ;
    u16* Wob = Wvb + WZ;
    u16* Kw  = Wob + WZ;
    u16* Qw  = Kw + SZ;
    u16* Ow  = Qw + SZ;
    u16* VTw = (u16*)d_out;   // V^T [B,H,D,T] scratch in d_out

    cvt_all<<<dim3(3360), 256, 0, stream>>>(
        x, Wk, Wq, Wv, Wo, xb, Wkb, Wqb, Wvb, Wob);

    gemm_qkv<<<dim3(1152), 256, 0, stream>>>(xb, Wkb, Wvb, Wqb, Kw, VTw, Qw);

    attn_kernel<<<dim3(1536), 256, 0, stream>>>(Qw, Kw, VTw, Ow);

    gemm_out<<<dim3(768), 256, 0, stream>>>(Ow, Wob, bo, out);
}